// Round 2
// baseline (1177.149 us; speedup 1.0000x reference)
//
#include <hip/hip_runtime.h>

// ---------------- types ----------------
typedef _Float16 half_t;
typedef _Float16 f16x8 __attribute__((ext_vector_type(8)));
typedef _Float16 f16x4 __attribute__((ext_vector_type(4)));
typedef float    f32x4 __attribute__((ext_vector_type(4)));

#define MFMA16(a, b, c) __builtin_amdgcn_mfma_f32_16x16x32_f16((a), (b), (c), 0, 0, 0)

// Problem constants
#define BB   8
#define SS   512
#define DD   512
#define HH   8
#define DKK  64
#define DFFN 2048
#define MTOT 4096   // B*S

// async global->LDS, 16B per lane; lds dst must be wave-uniform base (lane*16 auto)
__device__ __forceinline__ void gload16(const half_t* g, half_t* l) {
    __builtin_amdgcn_global_load_lds((const __attribute__((address_space(1))) void*)g,
                                     (__attribute__((address_space(3))) void*)l, 16, 0, 0);
}

// ---------------- weight transpose: W[K][N] f32 -> Wt[N][K] f16 ----------------
// grid (N/32, K/32, nmat), block (32,8)
__global__ __launch_bounds__(256) void wtrans(const float* __restrict__ W,
                                              half_t* __restrict__ Wt, int K, int N) {
    const long z = blockIdx.z;
    W  += z * (long)K * N;
    Wt += z * (long)K * N;
    __shared__ float t[32][33];
    const int n0 = blockIdx.x * 32, k0 = blockIdx.y * 32;
    const int tx = threadIdx.x, ty = threadIdx.y;
#pragma unroll
    for (int i = 0; i < 4; i++)
        t[ty + i * 8][tx] = W[(long)(k0 + ty + i * 8) * N + n0 + tx];
    __syncthreads();
#pragma unroll
    for (int i = 0; i < 4; i++)
        Wt[(long)(n0 + ty + i * 8) * K + k0 + tx] = (half_t)t[tx][ty + i * 8];
}

// ---------------- V transpose per head: V[b*S+s][h*64+d] -> Vt[(b*8+h)*64+d][s] ----------------
// grid (S/32, 2, B*H), block (32,8)
__global__ __launch_bounds__(256) void vtrans(const half_t* __restrict__ V,
                                              half_t* __restrict__ Vt, int Lk) {
    const int z = blockIdx.z, b = z >> 3, h = z & 7;
    const int s0 = blockIdx.x * 32, d0 = blockIdx.y * 32;
    const int tx = threadIdx.x, ty = threadIdx.y;
    __shared__ half_t t[32][33];
#pragma unroll
    for (int i = 0; i < 4; i++)
        t[ty + i * 8][tx] = V[(long)(b * Lk + s0 + ty + i * 8) * DD + h * 64 + d0 + tx];
    __syncthreads();
#pragma unroll
    for (int i = 0; i < 4; i++)
        Vt[(long)(z * 64 + d0 + ty + i * 8) * Lk + s0 + tx] = t[tx][ty + i * 8];
}

// ---------------- positional encoding add: out f16 = src f32 + PE ----------------
__global__ __launch_bounds__(256) void posenc_k(const float* __restrict__ src,
                                                half_t* __restrict__ out) {
    const int idx = blockIdx.x * 256 + threadIdx.x;
    const long f = (long)idx * 4;
    const int d0 = (int)(f & 511);
    const int srow = (int)((f >> 9) & 511);
    float4 v = *(const float4*)(src + f);
    const float cexp = -0.0359778926f;  // -2*ln(10000)/512
    const int p0 = d0 >> 1;
    const float a0 = (float)srow * __expf(cexp * (float)p0);
    const float a1 = (float)srow * __expf(cexp * (float)(p0 + 1));
    v.x += __sinf(a0);
    v.y += __cosf(a0);
    v.z += __sinf(a1);
    v.w += __cosf(a1);
    f16x4 h;
    h[0] = (half_t)v.x; h[1] = (half_t)v.y; h[2] = (half_t)v.z; h[3] = (half_t)v.w;
    *(f16x4*)(out + f) = h;
}

// ---------------- layernorm (+optional residual), row length 512 ----------------
// grid 1024 x 256 (wave per row). out = LN(X (+R)) * g + b
template <int HASRES, int F32OUT>
__global__ __launch_bounds__(256) void ln_k(const half_t* __restrict__ X,
                                            const half_t* __restrict__ R,
                                            const float* __restrict__ gam,
                                            const float* __restrict__ bet,
                                            void* __restrict__ out) {
    const int wid = threadIdx.x >> 6, lane = threadIdx.x & 63;
    const long row = blockIdx.x * 4 + wid;
    const int c = lane * 8;
    float v[8];
    f16x8 xv = *(const f16x8*)(X + row * 512 + c);
    if (HASRES) {
        f16x8 rv = *(const f16x8*)(R + row * 512 + c);
#pragma unroll
        for (int i = 0; i < 8; i++) v[i] = (float)xv[i] + (float)rv[i];
    } else {
#pragma unroll
        for (int i = 0; i < 8; i++) v[i] = (float)xv[i];
    }
    float s = 0.f, sq = 0.f;
#pragma unroll
    for (int i = 0; i < 8; i++) { s += v[i]; sq += v[i] * v[i]; }
#pragma unroll
    for (int m = 1; m < 64; m <<= 1) {
        s += __shfl_xor(s, m);
        sq += __shfl_xor(sq, m);
    }
    const float mu = s * (1.f / 512.f);
    const float var = sq * (1.f / 512.f) - mu * mu;
    const float rstd = rsqrtf(var + 1e-5f);
    float4 g0 = *(const float4*)(gam + c), g1 = *(const float4*)(gam + c + 4);
    float4 b0 = *(const float4*)(bet + c), b1 = *(const float4*)(bet + c + 4);
    float gg[8] = {g0.x, g0.y, g0.z, g0.w, g1.x, g1.y, g1.z, g1.w};
    float bb[8] = {b0.x, b0.y, b0.z, b0.w, b1.x, b1.y, b1.z, b1.w};
    if (F32OUT) {
        float* o = (float*)out + row * 512 + c;
        float4 o0, o1;
        o0.x = (v[0] - mu) * rstd * gg[0] + bb[0];
        o0.y = (v[1] - mu) * rstd * gg[1] + bb[1];
        o0.z = (v[2] - mu) * rstd * gg[2] + bb[2];
        o0.w = (v[3] - mu) * rstd * gg[3] + bb[3];
        o1.x = (v[4] - mu) * rstd * gg[4] + bb[4];
        o1.y = (v[5] - mu) * rstd * gg[5] + bb[5];
        o1.z = (v[6] - mu) * rstd * gg[6] + bb[6];
        o1.w = (v[7] - mu) * rstd * gg[7] + bb[7];
        *(float4*)o = o0;
        *(float4*)(o + 4) = o1;
    } else {
        f16x8 hv;
#pragma unroll
        for (int i = 0; i < 8; i++) hv[i] = (half_t)((v[i] - mu) * rstd * gg[i] + bb[i]);
        *(f16x8*)((half_t*)out + row * 512 + c) = hv;
    }
}

// ---------------- GEMM: C[M][N] f16 = A[M][K] f16 @ Wt[N][K]^T + bias (opt ReLU) ----------------
// tile (MR*32)x64xBK32, 256 thr (4 waves, 2x2), double-buffered LDS, global_load_lds w16.
// MR=4 -> BM=128 (use when grid is already >= 2 blocks/CU); MR=2 -> BM=64 (occupancy for
// single-matrix N=512 GEMMs: 512 blocks = 2/CU instead of 256 = 1/CU).
template <int MR, int RELU>
__global__ __launch_bounds__(256) void gemm_k(const half_t* __restrict__ A,
                                              const half_t* __restrict__ Wt,
                                              const float* __restrict__ bias,
                                              half_t* __restrict__ C, int M, int N, int K,
                                              long wzs, long bzs, long czs) {
    constexpr int BM = MR * 32;
    __shared__ half_t smem[2][(BM + 64) * 32];
    const int z = blockIdx.z;
    const half_t* Wz = Wt + (long)z * wzs;
    const float* bz = bias + (long)z * bzs;
    half_t* Cz = C + (long)z * czs;
    const int m0 = blockIdx.x * BM, n0 = blockIdx.y * 64;
    const int tid = threadIdx.x, wid = tid >> 6, lane = tid & 63;
    const int g = lane >> 4, l16 = lane & 15;
    const int wr = wid >> 1, wc = wid & 1;
    const int nk = K >> 5;

    f32x4 acc[MR][2];
#pragma unroll
    for (int i = 0; i < MR; i++)
#pragma unroll
        for (int j = 0; j < 2; j++)
#pragma unroll
            for (int e = 0; e < 4; e++) acc[i][j][e] = 0.f;

    auto stage = [&](int buf, int kt) {
        half_t* sA = smem[buf];
        half_t* sB = smem[buf] + BM * 32;
        const int k0 = kt << 5;
#pragma unroll
        for (int i = 0; i < MR / 2; i++) {  // A: BM*4 chunks of 8 halfs
            const int c = i * 256 + wid * 64 + lane;
            gload16(A + (long)(m0 + (c >> 2)) * K + k0 + (c & 3) * 8,
                    sA + (i * 256 + wid * 64) * 8);
        }
        const int c = wid * 64 + lane;  // B: 256 chunks
        gload16(Wz + (long)(n0 + (c >> 2)) * K + k0 + (c & 3) * 8, sB + (wid * 64) * 8);
    };

    stage(0, 0);
    __syncthreads();
    int buf = 0;
    for (int kt = 0; kt < nk; kt++) {
        if (kt + 1 < nk) stage(buf ^ 1, kt + 1);
        const half_t* sA = smem[buf];
        const half_t* sB = smem[buf] + BM * 32;
        f16x8 af[MR], bf[2];
#pragma unroll
        for (int mr = 0; mr < MR; mr++) {
            const int row = wr * (MR * 16) + mr * 16 + l16;
            af[mr] = *(const f16x8*)(sA + row * 32 + g * 8);
        }
#pragma unroll
        for (int nr = 0; nr < 2; nr++) {
            const int row = wc * 32 + nr * 16 + l16;
            bf[nr] = *(const f16x8*)(sB + row * 32 + g * 8);
        }
#pragma unroll
        for (int mr = 0; mr < MR; mr++)
#pragma unroll
            for (int nr = 0; nr < 2; nr++)
                acc[mr][nr] = MFMA16(af[mr], bf[nr], acc[mr][nr]);
        __syncthreads();
        buf ^= 1;
    }

#pragma unroll
    for (int nr = 0; nr < 2; nr++) {
        const int n = n0 + wc * 32 + nr * 16 + l16;
        const float bv = bz[n];
#pragma unroll
        for (int mr = 0; mr < MR; mr++) {
#pragma unroll
            for (int e = 0; e < 4; e++) {
                const int m = m0 + wr * (MR * 16) + mr * 16 + g * 4 + e;
                float v = acc[mr][nr][e] + bv;
                if (RELU) v = fmaxf(v, 0.f);
                Cz[(long)m * N + n] = (half_t)v;
            }
        }
    }
}

// ---------------- fused flash attention ----------------
// grid (Lq/64, H, B), 256 thr (4 waves; wave = 16 q rows). K/V tiles 64x64 f16.
// Q/K/V LDS rows are 128B => XOR-swizzle chunks via pre-swizzled GLOBAL source (m173).
template <int CAUSAL>
__global__ __launch_bounds__(256) void flash_k(const half_t* __restrict__ Qb,
                                               const half_t* __restrict__ Kb,
                                               const half_t* __restrict__ Vt,
                                               half_t* __restrict__ Ob, int Lq, int Lk) {
    __shared__ half_t sQ[64 * 64], sK[64 * 64], sV[64 * 64];
    __shared__ half_t sP[4][16 * 88];  // stride 88 halves: 16B aligned, 2-way banks
    const int qt = blockIdx.x, h = blockIdx.y, b = blockIdx.z;
    const int tid = threadIdx.x, wid = tid >> 6, lane = tid & 63;
    const int g = lane >> 4, l16 = lane & 15;

#pragma unroll
    for (int i = 0; i < 2; i++) {  // stage Q once
        const int c = i * 256 + wid * 64 + lane;
        const int r = c >> 3, j = c & 7, js = j ^ (r & 7);
        gload16(Qb + (long)(b * Lq + qt * 64 + r) * DD + h * 64 + js * 8,
                sQ + (i * 256 + wid * 64) * 8);
    }

    float m_e[4], l_e[4];
#pragma unroll
    for (int e = 0; e < 4; e++) { m_e[e] = -1e30f; l_e[e] = 0.f; }
    f32x4 o[4];
#pragma unroll
    for (int d = 0; d < 4; d++)
#pragma unroll
        for (int e = 0; e < 4; e++) o[d][e] = 0.f;

    const int nkv = CAUSAL ? (qt + 1) : (Lk >> 6);
    for (int kvt = 0; kvt < nkv; kvt++) {
#pragma unroll
        for (int i = 0; i < 2; i++) {  // stage K, Vt tiles (swizzled source)
            const int c = i * 256 + wid * 64 + lane;
            const int r = c >> 3, j = c & 7, js = j ^ (r & 7);
            gload16(Kb + (long)(b * Lk + kvt * 64 + r) * DD + h * 64 + js * 8,
                    sK + (i * 256 + wid * 64) * 8);
            gload16(Vt + (long)((b * HH + h) * 64 + r) * Lk + kvt * 64 + js * 8,
                    sV + (i * 256 + wid * 64) * 8);
        }
        __syncthreads();

        f32x4 s[4];
#pragma unroll
        for (int nr = 0; nr < 4; nr++)
#pragma unroll
            for (int e = 0; e < 4; e++) s[nr][e] = 0.f;
#pragma unroll
        for (int k0 = 0; k0 < 2; k0++) {
            const int qrow = wid * 16 + l16;
            f16x8 aq = *(const f16x8*)(sQ + qrow * 64 + (((k0 * 4 + g) ^ (qrow & 7)) * 8));
#pragma unroll
            for (int nr = 0; nr < 4; nr++) {
                const int krow = nr * 16 + l16;
                f16x8 bk = *(const f16x8*)(sK + krow * 64 + (((k0 * 4 + g) ^ (krow & 7)) * 8));
                s[nr] = MFMA16(aq, bk, s[nr]);
            }
        }
        float mx[4];
#pragma unroll
        for (int e = 0; e < 4; e++) mx[e] = -1e30f;
#pragma unroll
        for (int nr = 0; nr < 4; nr++) {
#pragma unroll
            for (int e = 0; e < 4; e++) {
                float v = s[nr][e] * 0.125f;
                if (CAUSAL) {
                    const int q = qt * 64 + wid * 16 + g * 4 + e;
                    const int kv = kvt * 64 + nr * 16 + l16;
                    if (kv > q) v = -1e9f;
                }
                s[nr][e] = v;
                mx[e] = fmaxf(mx[e], v);
            }
        }
#pragma unroll
        for (int e = 0; e < 4; e++) {
            float v = mx[e];
            v = fmaxf(v, __shfl_xor(v, 1));
            v = fmaxf(v, __shfl_xor(v, 2));
            v = fmaxf(v, __shfl_xor(v, 4));
            v = fmaxf(v, __shfl_xor(v, 8));
            mx[e] = v;
        }
        float al[4], rs[4];
#pragma unroll
        for (int e = 0; e < 4; e++) {
            const float mn = fmaxf(m_e[e], mx[e]);
            al[e] = __expf(m_e[e] - mn);
            m_e[e] = mn;
            rs[e] = 0.f;
        }
#pragma unroll
        for (int nr = 0; nr < 4; nr++) {
#pragma unroll
            for (int e = 0; e < 4; e++) {
                const float p = __expf(s[nr][e] - m_e[e]);
                rs[e] += p;
                sP[wid][(g * 4 + e) * 88 + nr * 16 + l16] = (half_t)p;
            }
        }
#pragma unroll
        for (int e = 0; e < 4; e++) {
            float v = rs[e];
            v += __shfl_xor(v, 1);
            v += __shfl_xor(v, 2);
            v += __shfl_xor(v, 4);
            v += __shfl_xor(v, 8);
            l_e[e] = l_e[e] * al[e] + v;
        }
#pragma unroll
        for (int dr = 0; dr < 4; dr++)
#pragma unroll
            for (int e = 0; e < 4; e++) o[dr][e] *= al[e];
#pragma unroll
        for (int k0 = 0; k0 < 2; k0++) {  // PV
            f16x8 pa = *(const f16x8*)(&sP[wid][l16 * 88 + k0 * 32 + g * 8]);
#pragma unroll
            for (int dr = 0; dr < 4; dr++) {
                const int vrow = dr * 16 + l16;
                f16x8 vb = *(const f16x8*)(sV + vrow * 64 + (((k0 * 4 + g) ^ (vrow & 7)) * 8));
                o[dr] = MFMA16(pa, vb, o[dr]);
            }
        }
        __syncthreads();
    }
#pragma unroll
    for (int dr = 0; dr < 4; dr++) {
#pragma unroll
        for (int e = 0; e < 4; e++) {
            const int q = qt * 64 + wid * 16 + g * 4 + e;
            const int d = h * 64 + dr * 16 + l16;
            Ob[(long)(b * Lq + q) * DD + d] = (half_t)(o[dr][e] / l_e[e]);
        }
    }
}

// ---------------- host side ----------------
#define MMAT 262144L   // 512*512 elems
#define FFMAT 1048576L // 512*2048 elems
#define ACTST 2097152L // 4096*512 elems

static inline void launch_gemm(hipStream_t st, const half_t* A, const half_t* Wt,
                               const float* b, half_t* C, int M, int N, int K, int nz,
                               long wzs, long bzs, long czs, bool relu, int bm) {
    dim3 grid(M / bm, N / 64, nz), blk(256);
    if (bm == 128) {
        if (relu)
            gemm_k<4, 1><<<grid, blk, 0, st>>>(A, Wt, b, C, M, N, K, wzs, bzs, czs);
        else
            gemm_k<4, 0><<<grid, blk, 0, st>>>(A, Wt, b, C, M, N, K, wzs, bzs, czs);
    } else {
        if (relu)
            gemm_k<2, 1><<<grid, blk, 0, st>>>(A, Wt, b, C, M, N, K, wzs, bzs, czs);
        else
            gemm_k<2, 0><<<grid, blk, 0, st>>>(A, Wt, b, C, M, N, K, wzs, bzs, czs);
    }
}

extern "C" void kernel_launch(void* const* d_in, const int* in_sizes, int n_in, void* d_out,
                              int out_size, void* d_ws, size_t ws_size, hipStream_t stream) {
    (void)in_sizes; (void)n_in; (void)out_size; (void)ws_size;
    const float* src = (const float*)d_in[0];
    const float* tgt = (const float*)d_in[1];
    const float* eaW = (const float*)d_in[2];
    const float* eab = (const float*)d_in[3];
    const float* ef1W = (const float*)d_in[4];
    const float* ef1b = (const float*)d_in[5];
    const float* ef2W = (const float*)d_in[6];
    const float* ef2b = (const float*)d_in[7];
    const float* elng = (const float*)d_in[8];
    const float* elnb = (const float*)d_in[9];
    const float* efng = (const float*)d_in[10];
    const float* efnb = (const float*)d_in[11];
    const float* dsW = (const float*)d_in[12];
    const float* dsb = (const float*)d_in[13];
    const float* dcW = (const float*)d_in[14];
    const float* dcb = (const float*)d_in[15];
    const float* df1W = (const float*)d_in[16];
    const float* df1b = (const float*)d_in[17];
    const float* df2W = (const float*)d_in[18];
    const float* df2b = (const float*)d_in[19];
    const float* dlng = (const float*)d_in[20];
    const float* dlnb = (const float*)d_in[21];
    const float* dfng = (const float*)d_in[22];
    const float* dfnb = (const float*)d_in[23];

    char* ws = (char*)d_ws;
    half_t* wtEA = (half_t*)(ws + 0);
    half_t* wtEF1 = (half_t*)(ws + 8388608);
    half_t* wtEF2 = (half_t*)(ws + 16777216);
    half_t* wtDS = (half_t*)(ws + 25165824);
    half_t* wtDC = (half_t*)(ws + 33554432);
    half_t* wtDF1 = (half_t*)(ws + 41943040);
    half_t* wtDF2 = (half_t*)(ws + 50331648);
    half_t* xb = (half_t*)(ws + 58720256);
    half_t* yb = (half_t*)(ws + 62914560);
    half_t* memb = (half_t*)(ws + 67108864);
    half_t* qb = (half_t*)(ws + 71303168);
    half_t* kb = (half_t*)(ws + 75497472);
    half_t* vb = (half_t*)(ws + 79691776);
    half_t* vtb = (half_t*)(ws + 83886080);
    half_t* ao = (half_t*)(ws + 88080384);
    half_t* pr = (half_t*)(ws + 92274688);
    half_t* ffh = (half_t*)(ws + 96468992);
    half_t* ff2 = (half_t*)(ws + 113246208);

    dim3 tb(32, 8);
    // weight transposes (fp32 -> f16 [N][K])
    wtrans<<<dim3(16, 16, 16), tb, 0, stream>>>(eaW, wtEA, 512, 512);
    wtrans<<<dim3(64, 16, 4), tb, 0, stream>>>(ef1W, wtEF1, 512, 2048);
    wtrans<<<dim3(16, 64, 4), tb, 0, stream>>>(ef2W, wtEF2, 2048, 512);
    wtrans<<<dim3(16, 16, 16), tb, 0, stream>>>(dsW, wtDS, 512, 512);
    wtrans<<<dim3(16, 16, 16), tb, 0, stream>>>(dcW, wtDC, 512, 512);
    wtrans<<<dim3(64, 16, 4), tb, 0, stream>>>(df1W, wtDF1, 512, 2048);
    wtrans<<<dim3(16, 64, 4), tb, 0, stream>>>(df2W, wtDF2, 2048, 512);

    posenc_k<<<2048, 256, 0, stream>>>(src, xb);
    posenc_k<<<2048, 256, 0, stream>>>(tgt, yb);

    // ----- encoder -----
    for (int l = 0; l < 4; l++) {
        launch_gemm(stream, xb, wtEA + (long)l * 4 * MMAT, eab + l * 2048, qb, MTOT, 512, 512,
                    3, MMAT, 512, ACTST, false, 128);
        vtrans<<<dim3(16, 2, 64), tb, 0, stream>>>(vb, vtb, 512);
        flash_k<0><<<dim3(8, 8, 8), 256, 0, stream>>>(qb, kb, vtb, ao, 512, 512);
        launch_gemm(stream, ao, wtEA + (long)(l * 4 + 3) * MMAT, eab + l * 2048 + 1536, pr,
                    MTOT, 512, 512, 1, 0, 0, 0, false, 64);
        ln_k<1, 0><<<1024, 256, 0, stream>>>(pr, xb, elng + l * 1024, elnb + l * 1024, xb);
        launch_gemm(stream, xb, wtEF1 + (long)l * FFMAT, ef1b + l * 2048, ffh, MTOT, 2048,
                    512, 1, 0, 0, 0, true, 128);
        launch_gemm(stream, ffh, wtEF2 + (long)l * FFMAT, ef2b + l * 512, ff2, MTOT, 512,
                    2048, 1, 0, 0, 0, false, 64);
        ln_k<1, 0><<<1024, 256, 0, stream>>>(ff2, xb, elng + l * 1024 + 512,
                                             elnb + l * 1024 + 512, xb);
    }
    ln_k<0, 0><<<1024, 256, 0, stream>>>(xb, nullptr, efng, efnb, memb);

    // ----- decoder -----
    for (int l = 0; l < 4; l++) {
        launch_gemm(stream, yb, wtDS + (long)l * 4 * MMAT, dsb + l * 2048, qb, MTOT, 512, 512,
                    3, MMAT, 512, ACTST, false, 128);
        vtrans<<<dim3(16, 2, 64), tb, 0, stream>>>(vb, vtb, 512);
        flash_k<1><<<dim3(8, 8, 8), 256, 0, stream>>>(qb, kb, vtb, ao, 512, 512);
        launch_gemm(stream, ao, wtDS + (long)(l * 4 + 3) * MMAT, dsb + l * 2048 + 1536, pr,
                    MTOT, 512, 512, 1, 0, 0, 0, false, 64);
        ln_k<1, 0><<<1024, 256, 0, stream>>>(pr, yb, dlng + l * 1536, dlnb + l * 1536, yb);
        launch_gemm(stream, yb, wtDC + (long)l * 4 * MMAT, dcb + l * 2048, qb, MTOT, 512, 512,
                    1, 0, 0, 0, false, 64);
        launch_gemm(stream, memb, wtDC + (long)(l * 4 + 1) * MMAT, dcb + l * 2048 + 512, kb,
                    MTOT, 512, 512, 2, MMAT, 512, ACTST, false, 128);
        vtrans<<<dim3(16, 2, 64), tb, 0, stream>>>(vb, vtb, 512);
        flash_k<0><<<dim3(8, 8, 8), 256, 0, stream>>>(qb, kb, vtb, ao, 512, 512);
        launch_gemm(stream, ao, wtDC + (long)(l * 4 + 3) * MMAT, dcb + l * 2048 + 1536, pr,
                    MTOT, 512, 512, 1, 0, 0, 0, false, 64);
        ln_k<1, 0><<<1024, 256, 0, stream>>>(pr, yb, dlng + l * 1536 + 512,
                                             dlnb + l * 1536 + 512, yb);
        launch_gemm(stream, yb, wtDF1 + (long)l * FFMAT, df1b + l * 2048, ffh, MTOT, 2048,
                    512, 1, 0, 0, 0, true, 128);
        launch_gemm(stream, ffh, wtDF2 + (long)l * FFMAT, df2b + l * 512, ff2, MTOT, 512,
                    2048, 1, 0, 0, 0, false, 64);
        ln_k<1, 0><<<1024, 256, 0, stream>>>(ff2, yb, dlng + l * 1536 + 1024,
                                             dlnb + l * 1536 + 1024, yb);
    }
    ln_k<0, 1><<<1024, 256, 0, stream>>>(yb, nullptr, dfng, dfnb, d_out);
}

// Round 3
// 1083.120 us; speedup vs baseline: 1.0868x; 1.0868x over previous
//
#include <hip/hip_runtime.h>

// ---------------- types ----------------
typedef _Float16 half_t;
typedef _Float16 f16x8 __attribute__((ext_vector_type(8)));
typedef _Float16 f16x4 __attribute__((ext_vector_type(4)));
typedef float    f32x4 __attribute__((ext_vector_type(4)));

#define MFMA16(a, b, c) __builtin_amdgcn_mfma_f32_16x16x32_f16((a), (b), (c), 0, 0, 0)

// Problem constants
#define BB   8
#define SS   512
#define DD   512
#define HH   8
#define DFFN 2048
#define MTOT 4096    // B*S
#define MMAT 262144L // 512*512 elems
#define FFMAT 1048576L
#define ACTST 2097152L // 4096*512 elems

// async global->LDS, 16B per lane; lds dst is wave-uniform base + lane*16
__device__ __forceinline__ void gload16(const half_t* g, half_t* l) {
    __builtin_amdgcn_global_load_lds((const __attribute__((address_space(1))) void*)g,
                                     (__attribute__((address_space(3))) void*)l, 16, 0, 0);
}

// ---------------- weight transpose: W[K][N] f32 -> Wt[N][K] f16 ----------------
__global__ __launch_bounds__(256) void wtrans(const float* __restrict__ W,
                                              half_t* __restrict__ Wt, int K, int N) {
    const long z = blockIdx.z;
    W += z * (long)K * N;
    Wt += z * (long)K * N;
    __shared__ float t[32][33];
    const int n0 = blockIdx.x * 32, k0 = blockIdx.y * 32;
    const int tx = threadIdx.x, ty = threadIdx.y;
#pragma unroll
    for (int i = 0; i < 4; i++)
        t[ty + i * 8][tx] = W[(long)(k0 + ty + i * 8) * N + n0 + tx];
    __syncthreads();
#pragma unroll
    for (int i = 0; i < 4; i++)
        Wt[(long)(n0 + ty + i * 8) * K + k0 + tx] = (half_t)t[tx][ty + i * 8];
}

// ---------------- V transpose per head: V[b*S+s][h*64+d] -> Vt[(b*8+h)*64+d][s] ----------------
__global__ __launch_bounds__(256) void vtrans(const half_t* __restrict__ V,
                                              half_t* __restrict__ Vt, int Lk) {
    const int z = blockIdx.z, b = z >> 3, h = z & 7;
    const int s0 = blockIdx.x * 32, d0 = blockIdx.y * 32;
    const int tx = threadIdx.x, ty = threadIdx.y;
    __shared__ half_t t[32][33];
#pragma unroll
    for (int i = 0; i < 4; i++)
        t[ty + i * 8][tx] = V[(long)(b * Lk + s0 + ty + i * 8) * DD + h * 64 + d0 + tx];
    __syncthreads();
#pragma unroll
    for (int i = 0; i < 4; i++)
        Vt[(long)(z * 64 + d0 + ty + i * 8) * Lk + s0 + tx] = t[tx][ty + i * 8];
}

// batched cross-attn V transpose over 4 layers: V_l = ckv + (2l+1)*ACTST
__global__ __launch_bounds__(256) void vtransc(const half_t* __restrict__ ckv,
                                               half_t* __restrict__ vtc) {
    const int zz = blockIdx.z, l = zz >> 6, z = zz & 63, b = z >> 3, h = z & 7;
    const half_t* V = ckv + (long)(2 * l + 1) * ACTST;
    half_t* Vt = vtc + (long)l * ACTST;
    const int s0 = blockIdx.x * 32, d0 = blockIdx.y * 32;
    const int tx = threadIdx.x, ty = threadIdx.y;
    __shared__ half_t t[32][33];
#pragma unroll
    for (int i = 0; i < 4; i++)
        t[ty + i * 8][tx] = V[(long)(b * SS + s0 + ty + i * 8) * DD + h * 64 + d0 + tx];
    __syncthreads();
#pragma unroll
    for (int i = 0; i < 4; i++)
        Vt[(long)(z * 64 + d0 + ty + i * 8) * SS + s0 + tx] = t[tx][ty + i * 8];
}

// ---------------- positional encoding add: out f16 = src f32 + PE ----------------
__global__ __launch_bounds__(256) void posenc_k(const float* __restrict__ src,
                                                half_t* __restrict__ out) {
    const int idx = blockIdx.x * 256 + threadIdx.x;
    const long f = (long)idx * 4;
    const int d0 = (int)(f & 511);
    const int srow = (int)((f >> 9) & 511);
    float4 v = *(const float4*)(src + f);
    const float cexp = -0.0359778926f;  // -2*ln(10000)/512
    const int p0 = d0 >> 1;
    const float a0 = (float)srow * __expf(cexp * (float)p0);
    const float a1 = (float)srow * __expf(cexp * (float)(p0 + 1));
    v.x += __sinf(a0);
    v.y += __cosf(a0);
    v.z += __sinf(a1);
    v.w += __cosf(a1);
    f16x4 h;
    h[0] = (half_t)v.x; h[1] = (half_t)v.y; h[2] = (half_t)v.z; h[3] = (half_t)v.w;
    *(f16x4*)(out + f) = h;
}

// ---------------- layernorm (+optional residual), row length 512 ----------------
template <int HASRES, int F32OUT>
__global__ __launch_bounds__(256) void ln_k(const half_t* __restrict__ X,
                                            const half_t* __restrict__ R,
                                            const float* __restrict__ gam,
                                            const float* __restrict__ bet,
                                            void* __restrict__ out) {
    const int wid = threadIdx.x >> 6, lane = threadIdx.x & 63;
    const long row = blockIdx.x * 4 + wid;
    const int c = lane * 8;
    float v[8];
    f16x8 xv = *(const f16x8*)(X + row * 512 + c);
    if (HASRES) {
        f16x8 rv = *(const f16x8*)(R + row * 512 + c);
#pragma unroll
        for (int i = 0; i < 8; i++) v[i] = (float)xv[i] + (float)rv[i];
    } else {
#pragma unroll
        for (int i = 0; i < 8; i++) v[i] = (float)xv[i];
    }
    float s = 0.f, sq = 0.f;
#pragma unroll
    for (int i = 0; i < 8; i++) { s += v[i]; sq += v[i] * v[i]; }
#pragma unroll
    for (int m = 1; m < 64; m <<= 1) {
        s += __shfl_xor(s, m);
        sq += __shfl_xor(sq, m);
    }
    const float mu = s * (1.f / 512.f);
    const float var = sq * (1.f / 512.f) - mu * mu;
    const float rstd = rsqrtf(var + 1e-5f);
    float4 g0 = *(const float4*)(gam + c), g1 = *(const float4*)(gam + c + 4);
    float4 b0 = *(const float4*)(bet + c), b1 = *(const float4*)(bet + c + 4);
    float gg[8] = {g0.x, g0.y, g0.z, g0.w, g1.x, g1.y, g1.z, g1.w};
    float bb[8] = {b0.x, b0.y, b0.z, b0.w, b1.x, b1.y, b1.z, b1.w};
    if (F32OUT) {
        float* o = (float*)out + row * 512 + c;
        float4 o0, o1;
        o0.x = (v[0] - mu) * rstd * gg[0] + bb[0];
        o0.y = (v[1] - mu) * rstd * gg[1] + bb[1];
        o0.z = (v[2] - mu) * rstd * gg[2] + bb[2];
        o0.w = (v[3] - mu) * rstd * gg[3] + bb[3];
        o1.x = (v[4] - mu) * rstd * gg[4] + bb[4];
        o1.y = (v[5] - mu) * rstd * gg[5] + bb[5];
        o1.z = (v[6] - mu) * rstd * gg[6] + bb[6];
        o1.w = (v[7] - mu) * rstd * gg[7] + bb[7];
        *(float4*)o = o0;
        *(float4*)(o + 4) = o1;
    } else {
        f16x8 hv;
#pragma unroll
        for (int i = 0; i < 8; i++) hv[i] = (half_t)((v[i] - mu) * rstd * gg[i] + bb[i]);
        *(f16x8*)((half_t*)out + row * 512 + c) = hv;
    }
}

// ---------------- GEMM: C[M][N] f16 = A[M][K] f16 @ Wt[N][K]^T + bias (opt ReLU) ----------------
// tile (MR*32)x64xBK64, 256 thr (4 waves, 2x2), double-buffered LDS, global_load_lds w16,
// XOR-chunk swizzle (source-side, m173) so 128B-stride rows don't bank-conflict.
// ZMAP=1: z -> decoder cross K/V matrix (l = z>>1, matrix = l*4+1+(z&1)).
template <int MR, int RELU, int ZMAP>
__global__ __launch_bounds__(256) void gemm_k(const half_t* __restrict__ A,
                                              const half_t* __restrict__ Wt,
                                              const float* __restrict__ bias,
                                              half_t* __restrict__ C, int M, int N, int K,
                                              long wzs, long bzs, long czs) {
    constexpr int BM = MR * 32;
    __shared__ half_t smem[2][(BM + 64) * 64];
    const int z = blockIdx.z;
    const half_t* Wz;
    const float* bz;
    half_t* Cz;
    if (ZMAP) {
        const int l = z >> 1, i = z & 1;
        Wz = Wt + (long)(l * 4 + 1 + i) * MMAT;
        bz = bias + l * 2048 + (1 + i) * 512;
        Cz = C + (long)z * czs;
    } else {
        Wz = Wt + (long)z * wzs;
        bz = bias + (long)z * bzs;
        Cz = C + (long)z * czs;
    }
    const int m0 = blockIdx.x * BM, n0 = blockIdx.y * 64;
    const int tid = threadIdx.x, wid = tid >> 6, lane = tid & 63;
    const int g = lane >> 4, l16 = lane & 15;
    const int wr = wid >> 1, wc = wid & 1;
    const int nk = K >> 6;

    f32x4 acc[MR][2];
#pragma unroll
    for (int i = 0; i < MR; i++)
#pragma unroll
        for (int j = 0; j < 2; j++)
#pragma unroll
            for (int e = 0; e < 4; e++) acc[i][j][e] = 0.f;

    auto stage = [&](int buf, int kt) {
        half_t* sA = smem[buf];
        half_t* sB = smem[buf] + BM * 64;
        const int k0 = kt << 6;
#pragma unroll
        for (int i = 0; i < MR; i++) {  // A: BM*8 chunks of 16B
            const int c = i * 256 + wid * 64 + lane;
            const int r = c >> 3, j = c & 7, js = j ^ (r & 7);
            gload16(A + (long)(m0 + r) * K + k0 + js * 8, sA + (i * 256 + wid * 64) * 8);
        }
#pragma unroll
        for (int i = 0; i < 2; i++) {  // B: 512 chunks
            const int c = i * 256 + wid * 64 + lane;
            const int r = c >> 3, j = c & 7, js = j ^ (r & 7);
            gload16(Wz + (long)(n0 + r) * K + k0 + js * 8, sB + (i * 256 + wid * 64) * 8);
        }
    };

    stage(0, 0);
    __syncthreads();
    int buf = 0;
    for (int kt = 0; kt < nk; kt++) {
        if (kt + 1 < nk) stage(buf ^ 1, kt + 1);
        const half_t* sA = smem[buf];
        const half_t* sB = smem[buf] + BM * 64;
#pragma unroll
        for (int kk = 0; kk < 2; kk++) {
            f16x8 af[MR], bf[2];
#pragma unroll
            for (int mr = 0; mr < MR; mr++) {
                const int row = wr * (MR * 16) + mr * 16 + l16;
                af[mr] = *(const f16x8*)(sA + row * 64 + (((kk * 4 + g) ^ (row & 7)) * 8));
            }
#pragma unroll
            for (int nr = 0; nr < 2; nr++) {
                const int row = wc * 32 + nr * 16 + l16;
                bf[nr] = *(const f16x8*)(sB + row * 64 + (((kk * 4 + g) ^ (row & 7)) * 8));
            }
#pragma unroll
            for (int mr = 0; mr < MR; mr++)
#pragma unroll
                for (int nr = 0; nr < 2; nr++)
                    acc[mr][nr] = MFMA16(af[mr], bf[nr], acc[mr][nr]);
        }
        __syncthreads();
        buf ^= 1;
    }

#pragma unroll
    for (int nr = 0; nr < 2; nr++) {
        const int n = n0 + wc * 32 + nr * 16 + l16;
        const float bv = bz[n];
#pragma unroll
        for (int mr = 0; mr < MR; mr++) {
#pragma unroll
            for (int e = 0; e < 4; e++) {
                const int m = m0 + wr * (MR * 16) + mr * 16 + g * 4 + e;
                float v = acc[mr][nr][e] + bv;
                if (RELU) v = fmaxf(v, 0.f);
                Cz[(long)m * N + n] = (half_t)v;
            }
        }
    }
}

// ---------------- fused flash attention (double-buffered K/V staging) ----------------
// grid (Lq/64, H, B), 256 thr (4 waves; wave = 16 q rows). K/V tiles 64x64 f16.
template <int CAUSAL>
__global__ __launch_bounds__(256) void flash_k(const half_t* __restrict__ Qb,
                                               const half_t* __restrict__ Kb,
                                               const half_t* __restrict__ Vt,
                                               half_t* __restrict__ Ob, int Lq, int Lk) {
    __shared__ half_t sQ[64 * 64];
    __shared__ half_t sK[2][64 * 64], sV[2][64 * 64];
    __shared__ half_t sP[4][16 * 88];  // stride 88 halves: 16B aligned, 2-way banks
    const int qt = blockIdx.x, h = blockIdx.y, b = blockIdx.z;
    const int tid = threadIdx.x, wid = tid >> 6, lane = tid & 63;
    const int g = lane >> 4, l16 = lane & 15;

#pragma unroll
    for (int i = 0; i < 2; i++) {  // stage Q once (swizzled source)
        const int c = i * 256 + wid * 64 + lane;
        const int r = c >> 3, j = c & 7, js = j ^ (r & 7);
        gload16(Qb + (long)(b * Lq + qt * 64 + r) * DD + h * 64 + js * 8,
                sQ + (i * 256 + wid * 64) * 8);
    }
    auto stage_kv = [&](int bu, int kvt) {
#pragma unroll
        for (int i = 0; i < 2; i++) {
            const int c = i * 256 + wid * 64 + lane;
            const int r = c >> 3, j = c & 7, js = j ^ (r & 7);
            gload16(Kb + (long)(b * Lk + kvt * 64 + r) * DD + h * 64 + js * 8,
                    sK[bu] + (i * 256 + wid * 64) * 8);
            gload16(Vt + (long)((b * HH + h) * 64 + r) * Lk + kvt * 64 + js * 8,
                    sV[bu] + (i * 256 + wid * 64) * 8);
        }
    };

    float m_e[4], l_e[4];
#pragma unroll
    for (int e = 0; e < 4; e++) { m_e[e] = -1e30f; l_e[e] = 0.f; }
    f32x4 o[4];
#pragma unroll
    for (int d = 0; d < 4; d++)
#pragma unroll
        for (int e = 0; e < 4; e++) o[d][e] = 0.f;

    const int nkv = CAUSAL ? (qt + 1) : (Lk >> 6);
    stage_kv(0, 0);
    __syncthreads();
    int buf = 0;
    for (int kvt = 0; kvt < nkv; kvt++) {
        if (kvt + 1 < nkv) stage_kv(buf ^ 1, kvt + 1);  // prefetch hides under compute
        const half_t* cK = sK[buf];
        const half_t* cV = sV[buf];

        f32x4 s[4];
#pragma unroll
        for (int nr = 0; nr < 4; nr++)
#pragma unroll
            for (int e = 0; e < 4; e++) s[nr][e] = 0.f;
#pragma unroll
        for (int k0 = 0; k0 < 2; k0++) {
            const int qrow = wid * 16 + l16;
            f16x8 aq = *(const f16x8*)(sQ + qrow * 64 + (((k0 * 4 + g) ^ (qrow & 7)) * 8));
#pragma unroll
            for (int nr = 0; nr < 4; nr++) {
                const int krow = nr * 16 + l16;
                f16x8 bk = *(const f16x8*)(cK + krow * 64 + (((k0 * 4 + g) ^ (krow & 7)) * 8));
                s[nr] = MFMA16(aq, bk, s[nr]);
            }
        }
        float mx[4];
#pragma unroll
        for (int e = 0; e < 4; e++) mx[e] = -1e30f;
#pragma unroll
        for (int nr = 0; nr < 4; nr++) {
#pragma unroll
            for (int e = 0; e < 4; e++) {
                float v = s[nr][e] * 0.125f;
                if (CAUSAL) {
                    const int q = qt * 64 + wid * 16 + g * 4 + e;
                    const int kv = kvt * 64 + nr * 16 + l16;
                    if (kv > q) v = -1e9f;
                }
                s[nr][e] = v;
                mx[e] = fmaxf(mx[e], v);
            }
        }
#pragma unroll
        for (int e = 0; e < 4; e++) {
            float v = mx[e];
            v = fmaxf(v, __shfl_xor(v, 1));
            v = fmaxf(v, __shfl_xor(v, 2));
            v = fmaxf(v, __shfl_xor(v, 4));
            v = fmaxf(v, __shfl_xor(v, 8));
            mx[e] = v;
        }
        float al[4], rs[4];
#pragma unroll
        for (int e = 0; e < 4; e++) {
            const float mn = fmaxf(m_e[e], mx[e]);
            al[e] = __expf(m_e[e] - mn);
            m_e[e] = mn;
            rs[e] = 0.f;
        }
#pragma unroll
        for (int nr = 0; nr < 4; nr++) {
#pragma unroll
            for (int e = 0; e < 4; e++) {
                const float p = __expf(s[nr][e] - m_e[e]);
                rs[e] += p;
                sP[wid][(g * 4 + e) * 88 + nr * 16 + l16] = (half_t)p;
            }
        }
#pragma unroll
        for (int e = 0; e < 4; e++) {
            float v = rs[e];
            v += __shfl_xor(v, 1);
            v += __shfl_xor(v, 2);
            v += __shfl_xor(v, 4);
            v += __shfl_xor(v, 8);
            l_e[e] = l_e[e] * al[e] + v;
        }
#pragma unroll
        for (int dr = 0; dr < 4; dr++)
#pragma unroll
            for (int e = 0; e < 4; e++) o[dr][e] *= al[e];
#pragma unroll
        for (int k0 = 0; k0 < 2; k0++) {  // PV
            f16x8 pa = *(const f16x8*)(&sP[wid][l16 * 88 + k0 * 32 + g * 8]);
#pragma unroll
            for (int dr = 0; dr < 4; dr++) {
                const int vrow = dr * 16 + l16;
                f16x8 vb = *(const f16x8*)(cV + vrow * 64 + (((k0 * 4 + g) ^ (vrow & 7)) * 8));
                o[dr] = MFMA16(pa, vb, o[dr]);
            }
        }
        __syncthreads();
        buf ^= 1;
    }
#pragma unroll
    for (int dr = 0; dr < 4; dr++) {
#pragma unroll
        for (int e = 0; e < 4; e++) {
            const int q = qt * 64 + wid * 16 + g * 4 + e;
            const int d = h * 64 + dr * 16 + l16;
            Ob[(long)(b * Lq + q) * DD + d] = (half_t)(o[dr][e] / l_e[e]);
        }
    }
}

// ---------------- host side ----------------
static inline void launch_gemm(hipStream_t st, const half_t* A, const half_t* Wt,
                               const float* b, half_t* C, int M, int N, int K, int nz,
                               long wzs, long bzs, long czs, bool relu, int bm) {
    dim3 grid(M / bm, N / 64, nz), blk(256);
    if (bm == 128) {
        if (relu)
            gemm_k<4, 1, 0><<<grid, blk, 0, st>>>(A, Wt, b, C, M, N, K, wzs, bzs, czs);
        else
            gemm_k<4, 0, 0><<<grid, blk, 0, st>>>(A, Wt, b, C, M, N, K, wzs, bzs, czs);
    } else {
        if (relu)
            gemm_k<2, 1, 0><<<grid, blk, 0, st>>>(A, Wt, b, C, M, N, K, wzs, bzs, czs);
        else
            gemm_k<2, 0, 0><<<grid, blk, 0, st>>>(A, Wt, b, C, M, N, K, wzs, bzs, czs);
    }
}

extern "C" void kernel_launch(void* const* d_in, const int* in_sizes, int n_in, void* d_out,
                              int out_size, void* d_ws, size_t ws_size, hipStream_t stream) {
    (void)in_sizes; (void)n_in; (void)out_size; (void)ws_size;
    const float* src = (const float*)d_in[0];
    const float* tgt = (const float*)d_in[1];
    const float* eaW = (const float*)d_in[2];
    const float* eab = (const float*)d_in[3];
    const float* ef1W = (const float*)d_in[4];
    const float* ef1b = (const float*)d_in[5];
    const float* ef2W = (const float*)d_in[6];
    const float* ef2b = (const float*)d_in[7];
    const float* elng = (const float*)d_in[8];
    const float* elnb = (const float*)d_in[9];
    const float* efng = (const float*)d_in[10];
    const float* efnb = (const float*)d_in[11];
    const float* dsW = (const float*)d_in[12];
    const float* dsb = (const float*)d_in[13];
    const float* dcW = (const float*)d_in[14];
    const float* dcb = (const float*)d_in[15];
    const float* df1W = (const float*)d_in[16];
    const float* df1b = (const float*)d_in[17];
    const float* df2W = (const float*)d_in[18];
    const float* df2b = (const float*)d_in[19];
    const float* dlng = (const float*)d_in[20];
    const float* dlnb = (const float*)d_in[21];
    const float* dfng = (const float*)d_in[22];
    const float* dfnb = (const float*)d_in[23];

    char* ws = (char*)d_ws;
    half_t* wtEA = (half_t*)(ws + 0);
    half_t* wtEF1 = (half_t*)(ws + 8388608);
    half_t* wtEF2 = (half_t*)(ws + 16777216);
    half_t* wtDS = (half_t*)(ws + 25165824);
    half_t* wtDC = (half_t*)(ws + 33554432);
    half_t* wtDF1 = (half_t*)(ws + 41943040);
    half_t* wtDF2 = (half_t*)(ws + 50331648);
    half_t* xb = (half_t*)(ws + 58720256);
    half_t* yb = (half_t*)(ws + 62914560);
    half_t* memb = (half_t*)(ws + 67108864);
    half_t* qb = (half_t*)(ws + 71303168);
    half_t* kb = (half_t*)(ws + 75497472);
    half_t* vb = (half_t*)(ws + 79691776);
    half_t* vtb = (half_t*)(ws + 83886080);
    half_t* ao = (half_t*)(ws + 88080384);
    half_t* pr = (half_t*)(ws + 92274688);
    half_t* ffh = (half_t*)(ws + 96468992);
    half_t* ff2 = (half_t*)(ws + 113246208);
    half_t* ckv = (half_t*)(ws + 134217728);  // 8 x ACTST (K0,V0,K1,V1,...)
    half_t* vtc = (half_t*)(ws + 167772160);  // 4 x ACTST transposed cross-V

    dim3 tb(32, 8);
    wtrans<<<dim3(16, 16, 16), tb, 0, stream>>>(eaW, wtEA, 512, 512);
    wtrans<<<dim3(64, 16, 4), tb, 0, stream>>>(ef1W, wtEF1, 512, 2048);
    wtrans<<<dim3(16, 64, 4), tb, 0, stream>>>(ef2W, wtEF2, 2048, 512);
    wtrans<<<dim3(16, 16, 16), tb, 0, stream>>>(dsW, wtDS, 512, 512);
    wtrans<<<dim3(16, 16, 16), tb, 0, stream>>>(dcW, wtDC, 512, 512);
    wtrans<<<dim3(64, 16, 4), tb, 0, stream>>>(df1W, wtDF1, 512, 2048);
    wtrans<<<dim3(16, 64, 4), tb, 0, stream>>>(df2W, wtDF2, 2048, 512);

    posenc_k<<<2048, 256, 0, stream>>>(src, xb);
    posenc_k<<<2048, 256, 0, stream>>>(tgt, yb);

    // ----- encoder -----
    for (int l = 0; l < 4; l++) {
        launch_gemm(stream, xb, wtEA + (long)l * 4 * MMAT, eab + l * 2048, qb, MTOT, 512, 512,
                    3, MMAT, 512, ACTST, false, 128);
        vtrans<<<dim3(16, 2, 64), tb, 0, stream>>>(vb, vtb, 512);
        flash_k<0><<<dim3(8, 8, 8), 256, 0, stream>>>(qb, kb, vtb, ao, 512, 512);
        launch_gemm(stream, ao, wtEA + (long)(l * 4 + 3) * MMAT, eab + l * 2048 + 1536, pr,
                    MTOT, 512, 512, 1, 0, 0, 0, false, 64);
        ln_k<1, 0><<<1024, 256, 0, stream>>>(pr, xb, elng + l * 1024, elnb + l * 1024, xb);
        launch_gemm(stream, xb, wtEF1 + (long)l * FFMAT, ef1b + l * 2048, ffh, MTOT, 2048,
                    512, 1, 0, 0, 0, true, 128);
        launch_gemm(stream, ffh, wtEF2 + (long)l * FFMAT, ef2b + l * 512, ff2, MTOT, 512,
                    2048, 1, 0, 0, 0, false, 64);
        ln_k<1, 0><<<1024, 256, 0, stream>>>(ff2, xb, elng + l * 1024 + 512,
                                             elnb + l * 1024 + 512, xb);
    }
    ln_k<0, 0><<<1024, 256, 0, stream>>>(xb, nullptr, efng, efnb, memb);

    // cross-attn K/V for ALL 4 decoder layers (depends only on memb): one batched GEMM
    gemm_k<4, 0, 1><<<dim3(32, 8, 8), 256, 0, stream>>>(memb, wtDC, dcb, ckv, MTOT, 512,
                                                        512, 0, 0, ACTST);
    vtransc<<<dim3(16, 2, 256), tb, 0, stream>>>(ckv, vtc);

    // ----- decoder -----
    for (int l = 0; l < 4; l++) {
        launch_gemm(stream, yb, wtDS + (long)l * 4 * MMAT, dsb + l * 2048, qb, MTOT, 512, 512,
                    3, MMAT, 512, ACTST, false, 128);
        vtrans<<<dim3(16, 2, 64), tb, 0, stream>>>(vb, vtb, 512);
        flash_k<1><<<dim3(8, 8, 8), 256, 0, stream>>>(qb, kb, vtb, ao, 512, 512);
        launch_gemm(stream, ao, wtDS + (long)(l * 4 + 3) * MMAT, dsb + l * 2048 + 1536, pr,
                    MTOT, 512, 512, 1, 0, 0, 0, false, 64);
        ln_k<1, 0><<<1024, 256, 0, stream>>>(pr, yb, dlng + l * 1536, dlnb + l * 1536, yb);
        launch_gemm(stream, yb, wtDC + (long)l * 4 * MMAT, dcb + l * 2048, qb, MTOT, 512, 512,
                    1, 0, 0, 0, false, 64);
        flash_k<0><<<dim3(8, 8, 8), 256, 0, stream>>>(qb, ckv + (long)(2 * l) * ACTST,
                                                      vtc + (long)l * ACTST, ao, 512, 512);
        launch_gemm(stream, ao, wtDC + (long)(l * 4 + 3) * MMAT, dcb + l * 2048 + 1536, pr,
                    MTOT, 512, 512, 1, 0, 0, 0, false, 64);
        ln_k<1, 0><<<1024, 256, 0, stream>>>(pr, yb, dlng + l * 1536 + 512,
                                             dlnb + l * 1536 + 512, yb);
        launch_gemm(stream, yb, wtDF1 + (long)l * FFMAT, df1b + l * 2048, ffh, MTOT, 2048,
                    512, 1, 0, 0, 0, true, 128);
        launch_gemm(stream, ffh, wtDF2 + (long)l * FFMAT, df2b + l * 512, ff2, MTOT, 512,
                    2048, 1, 0, 0, 0, false, 64);
        ln_k<1, 0><<<1024, 256, 0, stream>>>(ff2, yb, dlng + l * 1536 + 1024,
                                             dlnb + l * 1536 + 1024, yb);
    }
    ln_k<0, 1><<<1024, 256, 0, stream>>>(yb, nullptr, dfng, dfnb, d_out);
}

// Round 6
// 1058.279 us; speedup vs baseline: 1.1123x; 1.0235x over previous
//
#include <hip/hip_runtime.h>

// ---------------- types ----------------
typedef _Float16 half_t;
typedef _Float16 f16x8 __attribute__((ext_vector_type(8)));
typedef _Float16 f16x4 __attribute__((ext_vector_type(4)));
typedef float    f32x4 __attribute__((ext_vector_type(4)));

#define MFMA16(a, b, c) __builtin_amdgcn_mfma_f32_16x16x32_f16((a), (b), (c), 0, 0, 0)

// Problem constants
#define BB   8
#define SS   512
#define DD   512
#define HH   8
#define DFFN 2048
#define MTOT 4096    // B*S
#define MMAT 262144L // 512*512 elems
#define FFMAT 1048576L
#define ACTST 2097152L // 4096*512 elems

#define WAITV(n) asm volatile("s_waitcnt vmcnt(" #n ")" ::: "memory")
#define SBAR()   asm volatile("s_barrier" ::: "memory")

// async global->LDS, 16B per lane; lds dst is wave-uniform base + lane*16
__device__ __forceinline__ void gload16(const half_t* g, half_t* l) {
    __builtin_amdgcn_global_load_lds((const __attribute__((address_space(1))) void*)g,
                                     (__attribute__((address_space(3))) void*)l, 16, 0, 0);
}

// ---------------- weight transpose: W[K][N] f32 -> Wt[N][K] f16 ----------------
__global__ __launch_bounds__(256) void wtrans(const float* __restrict__ W,
                                              half_t* __restrict__ Wt, int K, int N) {
    const long z = blockIdx.z;
    W += z * (long)K * N;
    Wt += z * (long)K * N;
    __shared__ float t[32][33];
    const int n0 = blockIdx.x * 32, k0 = blockIdx.y * 32;
    const int tx = threadIdx.x, ty = threadIdx.y;
#pragma unroll
    for (int i = 0; i < 4; i++)
        t[ty + i * 8][tx] = W[(long)(k0 + ty + i * 8) * N + n0 + tx];
    __syncthreads();
#pragma unroll
    for (int i = 0; i < 4; i++)
        Wt[(long)(n0 + ty + i * 8) * K + k0 + tx] = (half_t)t[tx][ty + i * 8];
}

// ---------------- V transpose per head: V[b*S+s][h*64+d] -> Vt[(b*8+h)*64+d][s] ----------------
__global__ __launch_bounds__(256) void vtrans(const half_t* __restrict__ V,
                                              half_t* __restrict__ Vt, int Lk) {
    const int z = blockIdx.z, b = z >> 3, h = z & 7;
    const int s0 = blockIdx.x * 32, d0 = blockIdx.y * 32;
    const int tx = threadIdx.x, ty = threadIdx.y;
    __shared__ half_t t[32][33];
#pragma unroll
    for (int i = 0; i < 4; i++)
        t[ty + i * 8][tx] = V[(long)(b * Lk + s0 + ty + i * 8) * DD + h * 64 + d0 + tx];
    __syncthreads();
#pragma unroll
    for (int i = 0; i < 4; i++)
        Vt[(long)(z * 64 + d0 + ty + i * 8) * Lk + s0 + tx] = t[tx][ty + i * 8];
}

// batched cross-attn V transpose over 4 layers: V_l = ckv + (2l+1)*ACTST
__global__ __launch_bounds__(256) void vtransc(const half_t* __restrict__ ckv,
                                               half_t* __restrict__ vtc) {
    const int zz = blockIdx.z, l = zz >> 6, z = zz & 63, b = z >> 3, h = z & 7;
    const half_t* V = ckv + (long)(2 * l + 1) * ACTST;
    half_t* Vt = vtc + (long)l * ACTST;
    const int s0 = blockIdx.x * 32, d0 = blockIdx.y * 32;
    const int tx = threadIdx.x, ty = threadIdx.y;
    __shared__ half_t t[32][33];
#pragma unroll
    for (int i = 0; i < 4; i++)
        t[ty + i * 8][tx] = V[(long)(b * SS + s0 + ty + i * 8) * DD + h * 64 + d0 + tx];
    __syncthreads();
#pragma unroll
    for (int i = 0; i < 4; i++)
        Vt[(long)(z * 64 + d0 + ty + i * 8) * SS + s0 + tx] = t[tx][ty + i * 8];
}

// ---------------- positional encoding add: out f16 = src f32 + PE ----------------
__global__ __launch_bounds__(256) void posenc_k(const float* __restrict__ src,
                                                half_t* __restrict__ out) {
    const int idx = blockIdx.x * 256 + threadIdx.x;
    const long f = (long)idx * 4;
    const int d0 = (int)(f & 511);
    const int srow = (int)((f >> 9) & 511);
    float4 v = *(const float4*)(src + f);
    const float cexp = -0.0359778926f;  // -2*ln(10000)/512
    const int p0 = d0 >> 1;
    const float a0 = (float)srow * __expf(cexp * (float)p0);
    const float a1 = (float)srow * __expf(cexp * (float)(p0 + 1));
    v.x += __sinf(a0);
    v.y += __cosf(a0);
    v.z += __sinf(a1);
    v.w += __cosf(a1);
    f16x4 h;
    h[0] = (half_t)v.x; h[1] = (half_t)v.y; h[2] = (half_t)v.z; h[3] = (half_t)v.w;
    *(f16x4*)(out + f) = h;
}

// ---------------- layernorm (+optional residual), row length 512 ----------------
template <int HASRES, int F32OUT>
__global__ __launch_bounds__(256) void ln_k(const half_t* __restrict__ X,
                                            const half_t* __restrict__ R,
                                            const float* __restrict__ gam,
                                            const float* __restrict__ bet,
                                            void* __restrict__ out) {
    const int wid = threadIdx.x >> 6, lane = threadIdx.x & 63;
    const long row = blockIdx.x * 4 + wid;
    const int c = lane * 8;
    float v[8];
    f16x8 xv = *(const f16x8*)(X + row * 512 + c);
    if (HASRES) {
        f16x8 rv = *(const f16x8*)(R + row * 512 + c);
#pragma unroll
        for (int i = 0; i < 8; i++) v[i] = (float)xv[i] + (float)rv[i];
    } else {
#pragma unroll
        for (int i = 0; i < 8; i++) v[i] = (float)xv[i];
    }
    float s = 0.f, sq = 0.f;
#pragma unroll
    for (int i = 0; i < 8; i++) { s += v[i]; sq += v[i] * v[i]; }
#pragma unroll
    for (int m = 1; m < 64; m <<= 1) {
        s += __shfl_xor(s, m);
        sq += __shfl_xor(sq, m);
    }
    const float mu = s * (1.f / 512.f);
    const float var = sq * (1.f / 512.f) - mu * mu;
    const float rstd = rsqrtf(var + 1e-5f);
    float4 g0 = *(const float4*)(gam + c), g1 = *(const float4*)(gam + c + 4);
    float4 b0 = *(const float4*)(bet + c), b1 = *(const float4*)(bet + c + 4);
    float gg[8] = {g0.x, g0.y, g0.z, g0.w, g1.x, g1.y, g1.z, g1.w};
    float bb[8] = {b0.x, b0.y, b0.z, b0.w, b1.x, b1.y, b1.z, b1.w};
    if (F32OUT) {
        float* o = (float*)out + row * 512 + c;
        float4 o0, o1;
        o0.x = (v[0] - mu) * rstd * gg[0] + bb[0];
        o0.y = (v[1] - mu) * rstd * gg[1] + bb[1];
        o0.z = (v[2] - mu) * rstd * gg[2] + bb[2];
        o0.w = (v[3] - mu) * rstd * gg[3] + bb[3];
        o1.x = (v[4] - mu) * rstd * gg[4] + bb[4];
        o1.y = (v[5] - mu) * rstd * gg[5] + bb[5];
        o1.z = (v[6] - mu) * rstd * gg[6] + bb[6];
        o1.w = (v[7] - mu) * rstd * gg[7] + bb[7];
        *(float4*)o = o0;
        *(float4*)(o + 4) = o1;
    } else {
        f16x8 hv;
#pragma unroll
        for (int i = 0; i < 8; i++) hv[i] = (half_t)((v[i] - mu) * rstd * gg[i] + bb[i]);
        *(f16x8*)((half_t*)out + row * 512 + c) = hv;
    }
}

// ---------------- GEMM: C[M][N] f16 = A[M][K] f16 @ Wt[N][K]^T + bias (opt ReLU) ----------------
// tile (MR*32)x64xBK64, 256 thr (4 waves, 2x2). 3-buffer LDS, 2 tiles in flight,
// counted vmcnt (never 0 mid-loop), raw s_barrier — T3/T4 pattern.
// XOR-chunk swizzle via pre-swizzled global source (m173).
// ZMAP=1: z -> decoder cross K/V matrix (l = z>>1, matrix = l*4+1+(z&1)).
template <int MR, int RELU, int ZMAP>
__global__ __launch_bounds__(256) void gemm_k(const half_t* __restrict__ A,
                                              const half_t* __restrict__ Wt,
                                              const float* __restrict__ bias,
                                              half_t* __restrict__ C, int M, int N, int K,
                                              long wzs, long bzs, long czs) {
    constexpr int BM = MR * 32;
    __shared__ half_t smem[3][(BM + 64) * 64];
    const int z = blockIdx.z;
    const half_t* Wz;
    const float* bz;
    half_t* Cz;
    if (ZMAP) {
        const int l = z >> 1, i = z & 1;
        Wz = Wt + (long)(l * 4 + 1 + i) * MMAT;
        bz = bias + l * 2048 + (1 + i) * 512;
        Cz = C + (long)z * czs;
    } else {
        Wz = Wt + (long)z * wzs;
        bz = bias + (long)z * bzs;
        Cz = C + (long)z * czs;
    }
    const int m0 = blockIdx.x * BM, n0 = blockIdx.y * 64;
    const int tid = threadIdx.x, wid = tid >> 6, lane = tid & 63;
    const int g = lane >> 4, l16 = lane & 15;
    const int wr = wid >> 1, wc = wid & 1;
    const int nk = K >> 6;

    f32x4 acc[MR][2];
#pragma unroll
    for (int i = 0; i < MR; i++)
#pragma unroll
        for (int j = 0; j < 2; j++)
#pragma unroll
            for (int e = 0; e < 4; e++) acc[i][j][e] = 0.f;

    auto stage = [&](int s, int kt) {
        half_t* sA = smem[s];
        half_t* sB = smem[s] + BM * 64;
        const int k0 = kt << 6;
#pragma unroll
        for (int i = 0; i < MR; i++) {  // A: BM*8 chunks of 16B
            const int c = i * 256 + wid * 64 + lane;
            const int r = c >> 3, j = c & 7, js = j ^ (r & 7);
            gload16(A + (long)(m0 + r) * K + k0 + js * 8, sA + (i * 256 + wid * 64) * 8);
        }
#pragma unroll
        for (int i = 0; i < 2; i++) {  // B: 512 chunks
            const int c = i * 256 + wid * 64 + lane;
            const int r = c >> 3, j = c & 7, js = j ^ (r & 7);
            gload16(Wz + (long)(n0 + r) * K + k0 + js * 8, sB + (i * 256 + wid * 64) * 8);
        }
    };

    stage(0, 0);
    if (nk > 1) stage(1, 1);
    for (int kt = 0; kt < nk; kt++) {
        if (kt + 2 < nk) stage((kt + 2) % 3, kt + 2);
        // tile kt is the oldest in flight; keep kt+1/kt+2 outstanding (NLD = MR+2 per tile)
        if constexpr (MR == 4) {
            if (kt + 2 < nk) WAITV(12);
            else if (kt + 1 < nk) WAITV(6);
            else WAITV(0);
        } else {
            if (kt + 2 < nk) WAITV(8);
            else if (kt + 1 < nk) WAITV(4);
            else WAITV(0);
        }
        SBAR();
        const half_t* sA = smem[kt % 3];
        const half_t* sB = smem[kt % 3] + BM * 64;
#pragma unroll
        for (int kk = 0; kk < 2; kk++) {
            f16x8 af[MR], bf[2];
#pragma unroll
            for (int mr = 0; mr < MR; mr++) {
                const int row = wr * (MR * 16) + mr * 16 + l16;
                af[mr] = *(const f16x8*)(sA + row * 64 + (((kk * 4 + g) ^ (row & 7)) * 8));
            }
#pragma unroll
            for (int nr = 0; nr < 2; nr++) {
                const int row = wc * 32 + nr * 16 + l16;
                bf[nr] = *(const f16x8*)(sB + row * 64 + (((kk * 4 + g) ^ (row & 7)) * 8));
            }
#pragma unroll
            for (int mr = 0; mr < MR; mr++)
#pragma unroll
                for (int nr = 0; nr < 2; nr++)
                    acc[mr][nr] = MFMA16(af[mr], bf[nr], acc[mr][nr]);
        }
        SBAR();
    }

#pragma unroll
    for (int nr = 0; nr < 2; nr++) {
        const int n = n0 + wc * 32 + nr * 16 + l16;
        const float bv = bz[n];
#pragma unroll
        for (int mr = 0; mr < MR; mr++) {
#pragma unroll
            for (int e = 0; e < 4; e++) {
                const int m = m0 + wr * (MR * 16) + mr * 16 + g * 4 + e;
                float v = acc[mr][nr][e] + bv;
                if (RELU) v = fmaxf(v, 0.f);
                Cz[(long)m * N + n] = (half_t)v;
            }
        }
    }
}

// ---------------- fused flash attention (counted-vmcnt double-buffered K/V) ----------------
// grid (Lq/64, H, B), 256 thr (4 waves; wave = 16 q rows). K/V tiles 64x64 f16.
template <int CAUSAL>
__global__ __launch_bounds__(256) void flash_k(const half_t* __restrict__ Qb,
                                               const half_t* __restrict__ Kb,
                                               const half_t* __restrict__ Vt,
                                               half_t* __restrict__ Ob, int Lq, int Lk) {
    __shared__ half_t sQ[64 * 64];
    __shared__ half_t sK[2][64 * 64], sV[2][64 * 64];
    __shared__ half_t sP[4][16 * 88];  // stride 88 halves: 16B aligned, 2-way banks
    const int qt = blockIdx.x, h = blockIdx.y, b = blockIdx.z;
    const int tid = threadIdx.x, wid = tid >> 6, lane = tid & 63;
    const int g = lane >> 4, l16 = lane & 15;

#pragma unroll
    for (int i = 0; i < 2; i++) {  // stage Q once (swizzled source)
        const int c = i * 256 + wid * 64 + lane;
        const int r = c >> 3, j = c & 7, js = j ^ (r & 7);
        gload16(Qb + (long)(b * Lq + qt * 64 + r) * DD + h * 64 + js * 8,
                sQ + (i * 256 + wid * 64) * 8);
    }
    auto stage_kv = [&](int bu, int kvt) {
#pragma unroll
        for (int i = 0; i < 2; i++) {
            const int c = i * 256 + wid * 64 + lane;
            const int r = c >> 3, j = c & 7, js = j ^ (r & 7);
            gload16(Kb + (long)(b * Lk + kvt * 64 + r) * DD + h * 64 + js * 8,
                    sK[bu] + (i * 256 + wid * 64) * 8);
            gload16(Vt + (long)((b * HH + h) * 64 + r) * Lk + kvt * 64 + js * 8,
                    sV[bu] + (i * 256 + wid * 64) * 8);
        }
    };

    float m_e[4], l_e[4];
#pragma unroll
    for (int e = 0; e < 4; e++) { m_e[e] = -1e30f; l_e[e] = 0.f; }
    f32x4 o[4];
#pragma unroll
    for (int d = 0; d < 4; d++)
#pragma unroll
        for (int e = 0; e < 4; e++) o[d][e] = 0.f;

    const int nkv = CAUSAL ? (qt + 1) : (Lk >> 6);
    stage_kv(0, 0);
    int buf = 0;
    for (int kvt = 0; kvt < nkv; kvt++) {
        if (kvt + 1 < nkv) {
            stage_kv(buf ^ 1, kvt + 1);  // prefetch next tile
            WAITV(4);                    // oldest (tile kvt + Q) done; next stays in flight
        } else {
            WAITV(0);
        }
        SBAR();
        const half_t* cK = sK[buf];
        const half_t* cV = sV[buf];

        f32x4 s[4];
#pragma unroll
        for (int nr = 0; nr < 4; nr++)
#pragma unroll
            for (int e = 0; e < 4; e++) s[nr][e] = 0.f;
#pragma unroll
        for (int k0 = 0; k0 < 2; k0++) {
            const int qrow = wid * 16 + l16;
            f16x8 aq = *(const f16x8*)(sQ + qrow * 64 + (((k0 * 4 + g) ^ (qrow & 7)) * 8));
#pragma unroll
            for (int nr = 0; nr < 4; nr++) {
                const int krow = nr * 16 + l16;
                f16x8 bk = *(const f16x8*)(cK + krow * 64 + (((k0 * 4 + g) ^ (krow & 7)) * 8));
                s[nr] = MFMA16(aq, bk, s[nr]);
            }
        }
        float mx[4];
#pragma unroll
        for (int e = 0; e < 4; e++) mx[e] = -1e30f;
#pragma unroll
        for (int nr = 0; nr < 4; nr++) {
#pragma unroll
            for (int e = 0; e < 4; e++) {
                float v = s[nr][e] * 0.125f;
                if (CAUSAL) {
                    const int q = qt * 64 + wid * 16 + g * 4 + e;
                    const int kv = kvt * 64 + nr * 16 + l16;
                    if (kv > q) v = -1e9f;
                }
                s[nr][e] = v;
                mx[e] = fmaxf(mx[e], v);
            }
        }
#pragma unroll
        for (int e = 0; e < 4; e++) {
            float v = mx[e];
            v = fmaxf(v, __shfl_xor(v, 1));
            v = fmaxf(v, __shfl_xor(v, 2));
            v = fmaxf(v, __shfl_xor(v, 4));
            v = fmaxf(v, __shfl_xor(v, 8));
            mx[e] = v;
        }
        float al[4], rs[4];
#pragma unroll
        for (int e = 0; e < 4; e++) {
            const float mn = fmaxf(m_e[e], mx[e]);
            al[e] = __expf(m_e[e] - mn);
            m_e[e] = mn;
            rs[e] = 0.f;
        }
#pragma unroll
        for (int nr = 0; nr < 4; nr++) {
#pragma unroll
            for (int e = 0; e < 4; e++) {
                const float p = __expf(s[nr][e] - m_e[e]);
                rs[e] += p;
                sP[wid][(g * 4 + e) * 88 + nr * 16 + l16] = (half_t)p;
            }
        }
#pragma unroll
        for (int e = 0; e < 4; e++) {
            float v = rs[e];
            v += __shfl_xor(v, 1);
            v += __shfl_xor(v, 2);
            v += __shfl_xor(v, 4);
            v += __shfl_xor(v, 8);
            l_e[e] = l_e[e] * al[e] + v;
        }
#pragma unroll
        for (int dr = 0; dr < 4; dr++)
#pragma unroll
            for (int e = 0; e < 4; e++) o[dr][e] *= al[e];
#pragma unroll
        for (int k0 = 0; k0 < 2; k0++) {  // PV
            f16x8 pa = *(const f16x8*)(&sP[wid][l16 * 88 + k0 * 32 + g * 8]);
#pragma unroll
            for (int dr = 0; dr < 4; dr++) {
                const int vrow = dr * 16 + l16;
                f16x8 vb = *(const f16x8*)(cV + vrow * 64 + (((k0 * 4 + g) ^ (vrow & 7)) * 8));
                o[dr] = MFMA16(pa, vb, o[dr]);
            }
        }
        SBAR();
        buf ^= 1;
    }
#pragma unroll
    for (int dr = 0; dr < 4; dr++) {
#pragma unroll
        for (int e = 0; e < 4; e++) {
            const int q = qt * 64 + wid * 16 + g * 4 + e;
            const int d = h * 64 + dr * 16 + l16;
            Ob[(long)(b * Lq + q) * DD + d] = (half_t)(o[dr][e] / l_e[e]);
        }
    }
}

// ---------------- host side ----------------
static inline void launch_gemm(hipStream_t st, const half_t* A, const half_t* Wt,
                               const float* b, half_t* C, int M, int N, int K, int nz,
                               long wzs, long bzs, long czs, bool relu, int bm) {
    dim3 grid(M / bm, N / 64, nz), blk(256);
    if (bm == 128) {
        if (relu)
            gemm_k<4, 1, 0><<<grid, blk, 0, st>>>(A, Wt, b, C, M, N, K, wzs, bzs, czs);
        else
            gemm_k<4, 0, 0><<<grid, blk, 0, st>>>(A, Wt, b, C, M, N, K, wzs, bzs, czs);
    } else {
        if (relu)
            gemm_k<2, 1, 0><<<grid, blk, 0, st>>>(A, Wt, b, C, M, N, K, wzs, bzs, czs);
        else
            gemm_k<2, 0, 0><<<grid, blk, 0, st>>>(A, Wt, b, C, M, N, K, wzs, bzs, czs);
    }
}

extern "C" void kernel_launch(void* const* d_in, const int* in_sizes, int n_in, void* d_out,
                              int out_size, void* d_ws, size_t ws_size, hipStream_t stream) {
    (void)in_sizes; (void)n_in; (void)out_size; (void)ws_size;
    const float* src = (const float*)d_in[0];
    const float* tgt = (const float*)d_in[1];
    const float* eaW = (const float*)d_in[2];
    const float* eab = (const float*)d_in[3];
    const float* ef1W = (const float*)d_in[4];
    const float* ef1b = (const float*)d_in[5];
    const float* ef2W = (const float*)d_in[6];
    const float* ef2b = (const float*)d_in[7];
    const float* elng = (const float*)d_in[8];
    const float* elnb = (const float*)d_in[9];
    const float* efng = (const float*)d_in[10];
    const float* efnb = (const float*)d_in[11];
    const float* dsW = (const float*)d_in[12];
    const float* dsb = (const float*)d_in[13];
    const float* dcW = (const float*)d_in[14];
    const float* dcb = (const float*)d_in[15];
    const float* df1W = (const float*)d_in[16];
    const float* df1b = (const float*)d_in[17];
    const float* df2W = (const float*)d_in[18];
    const float* df2b = (const float*)d_in[19];
    const float* dlng = (const float*)d_in[20];
    const float* dlnb = (const float*)d_in[21];
    const float* dfng = (const float*)d_in[22];
    const float* dfnb = (const float*)d_in[23];

    char* ws = (char*)d_ws;
    half_t* wtEA = (half_t*)(ws + 0);
    half_t* wtEF1 = (half_t*)(ws + 8388608);
    half_t* wtEF2 = (half_t*)(ws + 16777216);
    half_t* wtDS = (half_t*)(ws + 25165824);
    half_t* wtDC = (half_t*)(ws + 33554432);
    half_t* wtDF1 = (half_t*)(ws + 41943040);
    half_t* wtDF2 = (half_t*)(ws + 50331648);
    half_t* xb = (half_t*)(ws + 58720256);
    half_t* yb = (half_t*)(ws + 62914560);
    half_t* memb = (half_t*)(ws + 67108864);
    half_t* qb = (half_t*)(ws + 71303168);
    half_t* kb = (half_t*)(ws + 75497472);
    half_t* vb = (half_t*)(ws + 79691776);
    half_t* vtb = (half_t*)(ws + 83886080);
    half_t* ao = (half_t*)(ws + 88080384);
    half_t* pr = (half_t*)(ws + 92274688);
    half_t* ffh = (half_t*)(ws + 96468992);
    half_t* ff2 = (half_t*)(ws + 113246208);
    half_t* ckv = (half_t*)(ws + 134217728);  // 8 x ACTST (K0,V0,K1,V1,...)
    half_t* vtc = (half_t*)(ws + 167772160);  // 4 x ACTST transposed cross-V

    dim3 tb(32, 8);
    wtrans<<<dim3(16, 16, 16), tb, 0, stream>>>(eaW, wtEA, 512, 512);
    wtrans<<<dim3(64, 16, 4), tb, 0, stream>>>(ef1W, wtEF1, 512, 2048);
    wtrans<<<dim3(16, 64, 4), tb, 0, stream>>>(ef2W, wtEF2, 2048, 512);
    wtrans<<<dim3(16, 16, 16), tb, 0, stream>>>(dsW, wtDS, 512, 512);
    wtrans<<<dim3(16, 16, 16), tb, 0, stream>>>(dcW, wtDC, 512, 512);
    wtrans<<<dim3(64, 16, 4), tb, 0, stream>>>(df1W, wtDF1, 512, 2048);
    wtrans<<<dim3(16, 64, 4), tb, 0, stream>>>(df2W, wtDF2, 2048, 512);

    posenc_k<<<2048, 256, 0, stream>>>(src, xb);
    posenc_k<<<2048, 256, 0, stream>>>(tgt, yb);

    // ----- encoder -----
    for (int l = 0; l < 4; l++) {
        launch_gemm(stream, xb, wtEA + (long)l * 4 * MMAT, eab + l * 2048, qb, MTOT, 512, 512,
                    3, MMAT, 512, ACTST, false, 128);
        vtrans<<<dim3(16, 2, 64), tb, 0, stream>>>(vb, vtb, 512);
        flash_k<0><<<dim3(8, 8, 8), 256, 0, stream>>>(qb, kb, vtb, ao, 512, 512);
        launch_gemm(stream, ao, wtEA + (long)(l * 4 + 3) * MMAT, eab + l * 2048 + 1536, pr,
                    MTOT, 512, 512, 1, 0, 0, 0, false, 64);
        ln_k<1, 0><<<1024, 256, 0, stream>>>(pr, xb, elng + l * 1024, elnb + l * 1024, xb);
        launch_gemm(stream, xb, wtEF1 + (long)l * FFMAT, ef1b + l * 2048, ffh, MTOT, 2048,
                    512, 1, 0, 0, 0, true, 128);
        launch_gemm(stream, ffh, wtEF2 + (long)l * FFMAT, ef2b + l * 512, ff2, MTOT, 512,
                    2048, 1, 0, 0, 0, false, 64);
        ln_k<1, 0><<<1024, 256, 0, stream>>>(ff2, xb, elng + l * 1024 + 512,
                                             elnb + l * 1024 + 512, xb);
    }
    ln_k<0, 0><<<1024, 256, 0, stream>>>(xb, nullptr, efng, efnb, memb);

    // cross-attn K/V for ALL 4 decoder layers (depends only on memb): one batched GEMM
    gemm_k<4, 0, 1><<<dim3(32, 8, 8), 256, 0, stream>>>(memb, wtDC, dcb, ckv, MTOT, 512,
                                                        512, 0, 0, ACTST);
    vtransc<<<dim3(16, 2, 256), tb, 0, stream>>>(ckv, vtc);

    // ----- decoder -----
    for (int l = 0; l < 4; l++) {
        launch_gemm(stream, yb, wtDS + (long)l * 4 * MMAT, dsb + l * 2048, qb, MTOT, 512, 512,
                    3, MMAT, 512, ACTST, false, 128);
        vtrans<<<dim3(16, 2, 64), tb, 0, stream>>>(vb, vtb, 512);
        flash_k<1><<<dim3(8, 8, 8), 256, 0, stream>>>(qb, kb, vtb, ao, 512, 512);
        launch_gemm(stream, ao, wtDS + (long)(l * 4 + 3) * MMAT, dsb + l * 2048 + 1536, pr,
                    MTOT, 512, 512, 1, 0, 0, 0, false, 64);
        ln_k<1, 0><<<1024, 256, 0, stream>>>(pr, yb, dlng + l * 1536, dlnb + l * 1536, yb);
        launch_gemm(stream, yb, wtDC + (long)l * 4 * MMAT, dcb + l * 2048, qb, MTOT, 512, 512,
                    1, 0, 0, 0, false, 64);
        flash_k<0><<<dim3(8, 8, 8), 256, 0, stream>>>(qb, ckv + (long)(2 * l) * ACTST,
                                                      vtc + (long)l * ACTST, ao, 512, 512);
        launch_gemm(stream, ao, wtDC + (long)(l * 4 + 3) * MMAT, dcb + l * 2048 + 1536, pr,
                    MTOT, 512, 512, 1, 0, 0, 0, false, 64);
        ln_k<1, 0><<<1024, 256, 0, stream>>>(pr, yb, dlng + l * 1536 + 512,
                                             dlnb + l * 1536 + 512, yb);
        launch_gemm(stream, yb, wtDF1 + (long)l * FFMAT, df1b + l * 2048, ffh, MTOT, 2048,
                    512, 1, 0, 0, 0, true, 128);
        launch_gemm(stream, ffh, wtDF2 + (long)l * FFMAT, df2b + l * 512, ff2, MTOT, 512,
                    2048, 1, 0, 0, 0, false, 64);
        ln_k<1, 0><<<1024, 256, 0, stream>>>(ff2, yb, dlng + l * 1536 + 1024,
                                             dlnb + l * 1536 + 1024, yb);
    }
    ln_k<0, 1><<<1024, 256, 0, stream>>>(yb, nullptr, dfng, dfnb, d_out);
}